// Round 1
// baseline (554.249 us; speedup 1.0000x reference)
//
#include <hip/hip_runtime.h>
#include <hip/hip_bf16.h>
#include <math.h>

// B=8 NC=64 N=128 DN=64 HS=HM=256 HMOD=64 MOD_IN=133 MOD_OUT=16512

typedef __bf16 bf16_t;
typedef __attribute__((ext_vector_type(4))) __bf16 bf16x4;
typedef __attribute__((ext_vector_type(8))) __bf16 bf16x8;
typedef __attribute__((ext_vector_type(4))) float f32x4;

__device__ __forceinline__ float fast_tanh(float x) {
  float e = __expf(2.0f * x);
  return 1.0f - 2.0f / (e + 1.0f);
}

__device__ __forceinline__ f32x4 mfma16(bf16x8 a, bf16x8 b, f32x4 c) {
  return __builtin_amdgcn_mfma_f32_16x16x32_bf16(a, b, c, 0, 0, 0);
}

// ---- K0: all f32->bf16 conversions in one kernel (3 block ranges) ----
// blocks [0,512): W -> Wbf + wstats (sum|W| per bc)
// blocks [512,2816): h (4194304) then nid (524288) -> bf16, 2048 elems/block
// blocks [2816,3264): shared MLP weights -> wbf
//   wbf layout: [0,49152) state_w1[256][192], [49152,65536) state_w2[64][256],
//               [65536,98304) msg_w1[256][128], [98304,114688) msg_w2[64][256]
__global__ __launch_bounds__(256) void k_prep(
    const float* __restrict__ W, const float* __restrict__ h,
    const float* __restrict__ nid, const float* __restrict__ sw1,
    const float* __restrict__ sw2, const float* __restrict__ mw1,
    const float* __restrict__ mw2, bf16_t* __restrict__ Wbf,
    bf16_t* __restrict__ hbf, bf16_t* __restrict__ nidbf,
    bf16_t* __restrict__ wbf, float* __restrict__ wstats) {
  int blk = blockIdx.x, t = threadIdx.x;
  if (blk < 512) {
    __shared__ float red[256];
    const float* Wp = W + (size_t)blk * 16384;
    bf16_t* op = Wbf + (size_t)blk * 16384;
    float asum = 0.f;
    for (int s = 0; s < 16; ++s) {
      int e = (s * 256 + t) * 4;
      f32x4 v = *(const f32x4*)(Wp + e);
      bf16x4 o;
#pragma unroll
      for (int u = 0; u < 4; ++u) { o[u] = (bf16_t)v[u]; asum += fabsf(v[u]); }
      *(bf16x4*)(op + e) = o;
    }
    red[t] = asum;
    __syncthreads();
    for (int s = 128; s > 0; s >>= 1) {
      if (t < s) red[t] += red[t + s];
      __syncthreads();
    }
    if (t == 0) wstats[blk] = red[0];
  } else if (blk < 2816) {
    int g = (blk - 512) * 2048 + t * 8;
    const float* src;
    bf16_t* dst;
    int off;
    if (g < 4194304) { src = h; dst = hbf; off = g; }
    else { src = nid; dst = nidbf; off = g - 4194304; }
    f32x4 v0 = *(const f32x4*)(src + off);
    f32x4 v1 = *(const f32x4*)(src + off + 4);
    bf16x8 o;
#pragma unroll
    for (int u = 0; u < 4; ++u) { o[u] = (bf16_t)v0[u]; o[u + 4] = (bf16_t)v1[u]; }
    *(bf16x8*)(dst + off) = o;
  } else {
    int i = (blk - 2816) * 256 + t;
    float v;
    if (i < 49152) v = sw1[i];
    else if (i < 65536) v = sw2[i - 49152];
    else if (i < 98304) v = mw1[i - 65536];
    else v = mw2[i - 98304];
    wbf[i] = (bf16_t)v;
  }
}

// ---- K1: fused received + state MLP + msg MLP. One block = one (b,c). ----
// 4 waves x 32 rows/wave. ONE barrier total (after msg-transpose + inject).
// rec lives only in LDS (bf16). All MFMA B-operands stream from global
// bf16 weights (per-XCD L2 resident). hs/hnew/recs rows are wave-private.
__global__ __launch_bounds__(256) void k_fused(
    const bf16_t* __restrict__ Wbf, const float* __restrict__ msg,
    const bf16_t* __restrict__ hbf, const bf16_t* __restrict__ nidbf,
    const float* __restrict__ Haug, const float* __restrict__ injw,
    const float* __restrict__ injb, const bf16_t* __restrict__ wbf,
    const float* __restrict__ sb1, const float* __restrict__ sb2,
    const float* __restrict__ msb1, const float* __restrict__ msb2,
    float* __restrict__ out_h, float* __restrict__ out_m) {
  int bc = blockIdx.x, c = bc & 63, b = bc >> 6;
  __shared__ bf16_t Mt[64][136];    // msg^T [d][j]
  __shared__ bf16_t recs[128][72];  // received, bf16 (wave-private rows)
  __shared__ bf16_t hs[128][72];    // hid1 / hid2 chunk (wave-private rows)
  __shared__ bf16_t hnew[128][72];  // h_new bf16 (wave-private rows)
  __shared__ float inj[128];
  int t = threadIdx.x;

  const float* Mp = msg + (size_t)bc * 8192;
  for (int s = 0; s < 8; ++s) {
    int e = (s * 256 + t) * 4;
    f32x4 v = *(const f32x4*)(Mp + e);
    int j = e >> 6, d = e & 63;
#pragma unroll
    for (int u = 0; u < 4; ++u) Mt[d + u][j] = (bf16_t)v[u];
  }
  if (t < 128) {
    const float* cell = Haug + (size_t)b * 4096 + c * 64;
    const float* iw = injw + (size_t)c * 8192 + t * 64;
    float a = injb[c * 128 + t];
    for (int k = 0; k < 64; ++k) a += cell[k] * iw[k];
    inj[t] = a;
  }
  __syncthreads();  // the only block-wide barrier

  int wave = t >> 6, l = t & 63, lr = l & 15, kg = l >> 4;
  int r0 = wave * 32;

  // ---- phase R: received = W @ msg, A streamed from global bf16 W ----
  const bf16_t* Wp = Wbf + (size_t)bc * 16384;
  f32x4 racc[2][4] = {};
#pragma unroll
  for (int ks = 0; ks < 4; ++ks) {
    int kof = ks * 32 + kg * 8;
    bf16x8 a0 = *(const bf16x8*)(Wp + (size_t)(r0 + lr) * 128 + kof);
    bf16x8 a1 = *(const bf16x8*)(Wp + (size_t)(r0 + 16 + lr) * 128 + kof);
#pragma unroll
    for (int ni = 0; ni < 4; ++ni) {
      bf16x8 bfr = *(const bf16x8*)&Mt[ni * 16 + lr][kof];
      racc[0][ni] = mfma16(a0, bfr, racc[0][ni]);
      racc[1][ni] = mfma16(a1, bfr, racc[1][ni]);
    }
  }
#pragma unroll
  for (int mi = 0; mi < 2; ++mi)
#pragma unroll
    for (int ni = 0; ni < 4; ++ni)
#pragma unroll
      for (int r = 0; r < 4; ++r) {
        int row = r0 + mi * 16 + kg * 4 + r, col = ni * 16 + lr;
        float v = racc[mi][ni][r];
        if (row < 2) v += inj[row * 64 + col];
        recs[row][col] = (bf16_t)v;
      }

  // ---- phase 1: h_new = tanh(W2 @ tanh(W1 @ [h|rec|nid] + b1) + b2) ----
  const bf16_t* hp = hbf + (size_t)bc * 8192;
  const bf16_t* np2 = nidbf + (size_t)c * 8192;
  bf16x8 aA[2][6];
#pragma unroll
  for (int mi = 0; mi < 2; ++mi) {
    int row = r0 + mi * 16 + lr;
#pragma unroll
    for (int ks = 0; ks < 6; ++ks) {
      int kof = ks * 32 + kg * 8;
      if (ks < 2)      aA[mi][ks] = *(const bf16x8*)(hp + (size_t)row * 64 + kof);
      else if (ks < 4) aA[mi][ks] = *(const bf16x8*)&recs[row][kof - 64];
      else             aA[mi][ks] = *(const bf16x8*)(np2 + (size_t)row * 64 + (kof - 128));
    }
  }
  const bf16_t* w1b = wbf;
  const bf16_t* w2b = wbf + 49152;
  const bf16_t* w3b = wbf + 65536;
  const bf16_t* w4b = wbf + 98304;
  f32x4 acc2[2][4] = {};
  for (int hc = 0; hc < 4; ++hc) {
    f32x4 a1[2][4] = {};
#pragma unroll
    for (int ks = 0; ks < 6; ++ks) {
      int kof = ks * 32 + kg * 8;
#pragma unroll
      for (int ni = 0; ni < 4; ++ni) {
        bf16x8 bfr = *(const bf16x8*)(w1b + (size_t)(hc * 64 + ni * 16 + lr) * 192 + kof);
        a1[0][ni] = mfma16(aA[0][ks], bfr, a1[0][ni]);
        a1[1][ni] = mfma16(aA[1][ks], bfr, a1[1][ni]);
      }
    }
#pragma unroll
    for (int mi = 0; mi < 2; ++mi)
#pragma unroll
      for (int ni = 0; ni < 4; ++ni) {
        float bias = sb1[hc * 64 + ni * 16 + lr];
#pragma unroll
        for (int r = 0; r < 4; ++r)
          hs[r0 + mi * 16 + kg * 4 + r][ni * 16 + lr] = (bf16_t)fast_tanh(a1[mi][ni][r] + bias);
      }
#pragma unroll
    for (int ks = 0; ks < 2; ++ks) {
      int kof = ks * 32 + kg * 8;
      bf16x8 af0 = *(const bf16x8*)&hs[r0 + lr][kof];
      bf16x8 af1 = *(const bf16x8*)&hs[r0 + 16 + lr][kof];
#pragma unroll
      for (int ni = 0; ni < 4; ++ni) {
        bf16x8 bfr = *(const bf16x8*)(w2b + (size_t)(ni * 16 + lr) * 256 + hc * 64 + kof);
        acc2[0][ni] = mfma16(af0, bfr, acc2[0][ni]);
        acc2[1][ni] = mfma16(af1, bfr, acc2[1][ni]);
      }
    }
  }
  float* ohp = out_h + (size_t)bc * 8192;
#pragma unroll
  for (int mi = 0; mi < 2; ++mi)
#pragma unroll
    for (int ni = 0; ni < 4; ++ni) {
      float bias = sb2[ni * 16 + lr];
#pragma unroll
      for (int r = 0; r < 4; ++r) {
        int row = r0 + mi * 16 + kg * 4 + r, col = ni * 16 + lr;
        float v = fast_tanh(acc2[mi][ni][r] + bias);
        ohp[row * 64 + col] = v;
        hnew[row][col] = (bf16_t)v;
      }
    }

  // ---- phase 2: msg_new; k: 0-63 h_new (hnew), 64-127 received (recs) ----
  bf16x8 aB[2][4];
#pragma unroll
  for (int mi = 0; mi < 2; ++mi) {
    int row = r0 + mi * 16 + lr;
#pragma unroll
    for (int ks = 0; ks < 4; ++ks) {
      int kof = ks * 32 + kg * 8;
      if (ks < 2) aB[mi][ks] = *(const bf16x8*)&hnew[row][kof];
      else        aB[mi][ks] = *(const bf16x8*)&recs[row][kof - 64];
    }
  }
  f32x4 acc3[2][4] = {};
  for (int hc = 0; hc < 4; ++hc) {
    f32x4 g3[2][4] = {};
#pragma unroll
    for (int ks = 0; ks < 4; ++ks) {
      int kof = ks * 32 + kg * 8;
#pragma unroll
      for (int ni = 0; ni < 4; ++ni) {
        bf16x8 bfr = *(const bf16x8*)(w3b + (size_t)(hc * 64 + ni * 16 + lr) * 128 + kof);
        g3[0][ni] = mfma16(aB[0][ks], bfr, g3[0][ni]);
        g3[1][ni] = mfma16(aB[1][ks], bfr, g3[1][ni]);
      }
    }
#pragma unroll
    for (int mi = 0; mi < 2; ++mi)
#pragma unroll
      for (int ni = 0; ni < 4; ++ni) {
        float bias = msb1[hc * 64 + ni * 16 + lr];
#pragma unroll
        for (int r = 0; r < 4; ++r)
          hs[r0 + mi * 16 + kg * 4 + r][ni * 16 + lr] = (bf16_t)fast_tanh(g3[mi][ni][r] + bias);
      }
#pragma unroll
    for (int ks = 0; ks < 2; ++ks) {
      int kof = ks * 32 + kg * 8;
      bf16x8 af0 = *(const bf16x8*)&hs[r0 + lr][kof];
      bf16x8 af1 = *(const bf16x8*)&hs[r0 + 16 + lr][kof];
#pragma unroll
      for (int ni = 0; ni < 4; ++ni) {
        bf16x8 bfr = *(const bf16x8*)(w4b + (size_t)(ni * 16 + lr) * 256 + hc * 64 + kof);
        acc3[0][ni] = mfma16(af0, bfr, acc3[0][ni]);
        acc3[1][ni] = mfma16(af1, bfr, acc3[1][ni]);
      }
    }
  }
  float* omp = out_m + (size_t)bc * 8192;
#pragma unroll
  for (int mi = 0; mi < 2; ++mi)
#pragma unroll
    for (int ni = 0; ni < 4; ++ni) {
      float bias = msb2[ni * 16 + lr];
#pragma unroll
      for (int r = 0; r < 4; ++r) {
        int row = r0 + mi * 16 + kg * 4 + r, col = ni * 16 + lr;
        omp[row * 64 + col] = fast_tanh(acc3[mi][ni][r] + bias);
      }
    }
}

// ---- K2: modulator input assembly + first layer (f32 exact) ----
// hidden written as [c][h][b] so k_apply reads become wave-uniform s_loads.
__global__ __launch_bounds__(256) void k_mod(
    const float* __restrict__ out_h, const float* __restrict__ out_m,
    const float* __restrict__ decay, const float* __restrict__ rdrift,
    const float* __restrict__ sml, const float* __restrict__ smf,
    const float* __restrict__ wstats, const float* __restrict__ mw1,
    const float* __restrict__ mb1, float* __restrict__ hidden) {
  int bc = blockIdx.x, c = bc & 63, b = bc >> 6;
  __shared__ float red[256];
  __shared__ float modin[133];
  int t = threadIdx.x, d = t & 63, q = t >> 6;
  const float* hp = out_h + (size_t)bc * 8192;
  const float* mp = out_m + (size_t)bc * 8192;
  float s1 = 0.f, s2 = 0.f;
  for (int i = q * 32; i < q * 32 + 32; ++i) { s1 += hp[i * 64 + d]; s2 += mp[i * 64 + d]; }
  red[t] = s1; __syncthreads();
  if (q == 0) modin[d] = (red[d] + red[64 + d] + red[128 + d] + red[192 + d]) * (1.f / 128.f);
  __syncthreads();
  red[t] = s2; __syncthreads();
  if (q == 0) modin[64 + d] = (red[d] + red[64 + d] + red[128 + d] + red[192 + d]) * (1.f / 128.f);
  __syncthreads();
  red[t] = (t < 128) ? decay[(size_t)bc * 128 + t] : 0.f;
  __syncthreads();
  for (int s = 128; s > 0; s >>= 1) {
    if (t < s) red[t] += red[t + s];
    __syncthreads();
  }
  if (t == 0) {
    modin[128] = wstats[bc] * (1.f / 16384.f);
    modin[129] = red[0] * (1.f / 128.f);
    modin[130] = rdrift[bc];
    modin[131] = sml[b];
    modin[132] = smf[b];
  }
  __syncthreads();
  if (t < 64) {
    const float* w = mw1 + (size_t)c * 133 * 64;
    float a = mb1[c * 64 + t];
    for (int i = 0; i < 133; ++i) a += modin[i] * w[i * 64 + t];
    hidden[((size_t)(c * 64 + t)) * 8 + b] = fast_tanh(a);
  }
}

// ---- K3: mod_out = hidden @ mod_w2 + b2; W_new = W + dW; decay_new ----
// hidden read via wave-uniform scalar loads; mod_w2 / outputs nontemporal.
__global__ __launch_bounds__(256) void k_apply(
    const float* __restrict__ hidden, const float* __restrict__ mw2,
    const float* __restrict__ mb2, const float* __restrict__ W,
    const float* __restrict__ decay, float* __restrict__ out_W,
    float* __restrict__ out_d) {
  int c = blockIdx.y, ch = blockIdx.x, t = threadIdx.x;
  int o = ch * 1024 + t * 4;
  if (o >= 16512) return;
  const float* w2 = mw2 + (size_t)c * 64 * 16512 + o;
  const float* hq = hidden + (size_t)c * 512;  // [h][b] for this c
  f32x4 bias = *(const f32x4*)(mb2 + (size_t)c * 16512 + o);
  f32x4 acc[8];
#pragma unroll
  for (int b = 0; b < 8; ++b) acc[b] = bias;
  for (int hh = 0; hh < 64; ++hh) {
    f32x4 wv = __builtin_nontemporal_load((const f32x4*)(w2 + (size_t)hh * 16512));
    f32x4 h0 = *(const f32x4*)(hq + hh * 8);
    f32x4 h1 = *(const f32x4*)(hq + hh * 8 + 4);
#pragma unroll
    for (int b = 0; b < 4; ++b) { acc[b] += h0[b] * wv; acc[b + 4] += h1[b] * wv; }
  }
  if (o < 16384) {
#pragma unroll
    for (int b = 0; b < 8; ++b) {
      size_t idx = (size_t)(b * 64 + c) * 16384 + o;
      f32x4 wv = *(const f32x4*)(W + idx);
      __builtin_nontemporal_store(wv + acc[b], (f32x4*)(out_W + idx));
    }
  } else {
    int i = o - 16384;
#pragma unroll
    for (int b = 0; b < 8; ++b) {
      size_t idx = (size_t)(b * 64 + c) * 128 + i;
      f32x4 dv = *(const f32x4*)(decay + idx);
      __builtin_nontemporal_store(dv + acc[b], (f32x4*)(out_d + idx));
    }
  }
}

extern "C" void kernel_launch(void* const* d_in, const int* in_sizes, int n_in,
                              void* d_out, int out_size, void* d_ws, size_t ws_size,
                              hipStream_t stream) {
  const float* h = (const float*)d_in[0];
  const float* msg = (const float*)d_in[1];
  const float* W = (const float*)d_in[2];
  const float* decay = (const float*)d_in[3];
  const float* rdrift = (const float*)d_in[4];
  const float* sml = (const float*)d_in[5];
  const float* smf = (const float*)d_in[6];
  const float* Haug = (const float*)d_in[7];
  const float* nid = (const float*)d_in[8];
  const float* sw1 = (const float*)d_in[9];
  const float* sb1 = (const float*)d_in[10];
  const float* sw2 = (const float*)d_in[11];
  const float* sb2 = (const float*)d_in[12];
  const float* mw1 = (const float*)d_in[13];
  const float* mb1 = (const float*)d_in[14];
  const float* mw2 = (const float*)d_in[15];
  const float* mb2 = (const float*)d_in[16];
  const float* injw = (const float*)d_in[17];
  const float* injb = (const float*)d_in[18];
  const float* modw1 = (const float*)d_in[19];
  const float* modb1 = (const float*)d_in[20];
  const float* modw2 = (const float*)d_in[21];
  const float* modb2 = (const float*)d_in[22];

  float* out = (float*)d_out;
  float* out_h = out;                // [8,64,128,64]
  float* out_m = out + 4194304;      // [8,64,128,64]
  float* out_W = out + 8388608;      // [8,64,128,128]
  float* out_d = out + 16777216;     // [8,64,128]

  char* wsb = (char*)d_ws;
  float* wstats = (float*)wsb;                        // 2 KB (pad to 4 KB)
  float* hidden = (float*)(wsb + 4096);               // 128 KB, [c][h][b]
  bf16_t* wbf = (bf16_t*)(wsb + 4096 + 131072);       // 224 KB (pad to 512K region)
  bf16_t* Wbf = (bf16_t*)(wsb + 524288);              // 16 MB
  bf16_t* hbf = (bf16_t*)(wsb + 524288 + 16777216);   // 8 MB
  bf16_t* nidbf = (bf16_t*)(wsb + 524288 + 16777216 + 8388608);  // 1 MB

  k_prep<<<3264, 256, 0, stream>>>(W, h, nid, sw1, sw2, mw1, mw2,
                                   Wbf, hbf, nidbf, wbf, wstats);
  k_fused<<<512, 256, 0, stream>>>(Wbf, msg, hbf, nidbf, Haug, injw, injb, wbf,
                                   sb1, sb2, mb1, mb2, out_h, out_m);
  k_mod<<<512, 256, 0, stream>>>(out_h, out_m, decay, rdrift, sml, smf, wstats,
                                 modw1, modb1, hidden);
  k_apply<<<dim3(17, 64), 256, 0, stream>>>(hidden, modw2, modb2, W, decay, out_W, out_d);
}

// Round 3
// 535.092 us; speedup vs baseline: 1.0358x; 1.0358x over previous
//
#include <hip/hip_runtime.h>
#include <hip/hip_bf16.h>
#include <math.h>

// B=8 NC=64 N=128 DN=64 HS=HM=256 HMOD=64 MOD_IN=133 MOD_OUT=16512

typedef __bf16 bf16_t;
typedef __attribute__((ext_vector_type(8))) __bf16 bf16x8;
typedef __attribute__((ext_vector_type(4))) float f32x4;

__device__ __forceinline__ float fast_tanh(float x) {
  float e = __expf(2.0f * x);
  return 1.0f - 2.0f / (e + 1.0f);
}

__device__ __forceinline__ f32x4 mfma16(bf16x8 a, bf16x8 b, f32x4 c) {
  return __builtin_amdgcn_mfma_f32_16x16x32_bf16(a, b, c, 0, 0, 0);
}

// load 8 consecutive f32, convert to bf16x8 fragment
__device__ __forceinline__ bf16x8 ldcvt8(const float* p) {
  f32x4 a = *(const f32x4*)p;
  f32x4 b = *(const f32x4*)(p + 4);
  bf16x8 o;
#pragma unroll
  for (int u = 0; u < 4; ++u) { o[u] = (bf16_t)a[u]; o[u + 4] = (bf16_t)b[u]; }
  return o;
}

// ---- K0: convert the 4 shared MLP weight matrices to bf16 (229 KB) ----
// wbf layout: [0,49152) state_w1[256][192], [49152,65536) state_w2[64][256],
//             [65536,98304) msg_w1[256][128], [98304,114688) msg_w2[64][256]
__global__ __launch_bounds__(256) void k_convert(
    const float* __restrict__ sw1, const float* __restrict__ sw2,
    const float* __restrict__ mw1, const float* __restrict__ mw2,
    bf16_t* __restrict__ out) {
  int i = blockIdx.x * 256 + threadIdx.x;
  float v;
  if (i < 49152) v = sw1[i];
  else if (i < 65536) v = sw2[i - 49152];
  else if (i < 98304) v = mw1[i - 65536];
  else v = mw2[i - 98304];
  out[i] = (bf16_t)v;
}

// ---- K1: received + state MLP + msg MLP + modulator input + mod layer 1 ----
// One block = one (b,c). 4 waves x 32 rows/wave. A-frags straight from f32
// global (in-register cvt). wstats folded into phase-R A loads. Per-block
// column reductions give h_mean/msg_mean for free (block owns all 128 rows).
__global__ __launch_bounds__(256) void k_fused(
    const float* __restrict__ W, const float* __restrict__ msg,
    const float* __restrict__ h, const float* __restrict__ nid,
    const float* __restrict__ Haug, const float* __restrict__ injw,
    const float* __restrict__ injb, const bf16_t* __restrict__ wbf,
    const float* __restrict__ sb1, const float* __restrict__ sb2,
    const float* __restrict__ msb1, const float* __restrict__ msb2,
    const float* __restrict__ decay, const float* __restrict__ rdrift,
    const float* __restrict__ sml, const float* __restrict__ smf,
    const float* __restrict__ mw1, const float* __restrict__ mb1,
    float* __restrict__ out_h, float* __restrict__ out_m,
    float* __restrict__ hidden) {
  int bc = blockIdx.x, c = bc & 63, b = bc >> 6;
  __shared__ bf16_t Mt[64][136];    // msg^T [d][j]
  __shared__ bf16_t recs[128][72];  // received bf16 (wave-private rows)
  __shared__ bf16_t hs[128][72];    // hid1 / hid2 chunk (wave-private rows)
  __shared__ bf16_t hnew[128][72];  // h_new bf16 (wave-private rows)
  __shared__ float inj[128];
  __shared__ float hsum[4][64];     // per-wave h_new column sums
  __shared__ float msum[4][64];     // per-wave msg_new column sums
  __shared__ float wsum[4];         // per-wave sum|W|
  __shared__ float modin[133];
  int t = threadIdx.x;

  const float* Mp = msg + (size_t)bc * 8192;
  for (int s = 0; s < 8; ++s) {
    int e = (s * 256 + t) * 4;
    f32x4 v = *(const f32x4*)(Mp + e);
    int j = e >> 6, d = e & 63;
#pragma unroll
    for (int u = 0; u < 4; ++u) Mt[d + u][j] = (bf16_t)v[u];
  }
  if (t < 128) {
    const float* cell = Haug + (size_t)b * 4096 + c * 64;
    const float* iw = injw + (size_t)c * 8192 + t * 64;
    float a = injb[c * 128 + t];
    for (int k = 0; k < 64; ++k) a += cell[k] * iw[k];
    inj[t] = a;
  }
  __syncthreads();  // Mt + inj ready

  int wave = t >> 6, l = t & 63, lr = l & 15, kg = l >> 4;
  int r0 = wave * 32;

  // ---- phase R: received = W @ msg; A from f32 W, |W| summed on the fly ----
  const float* Wp = W + (size_t)bc * 16384;
  float asum = 0.f;
  f32x4 racc[2][4] = {};
#pragma unroll
  for (int ks = 0; ks < 4; ++ks) {
    int kof = ks * 32 + kg * 8;
    const float* p0 = Wp + (size_t)(r0 + lr) * 128 + kof;
    const float* p1 = Wp + (size_t)(r0 + 16 + lr) * 128 + kof;
    f32x4 x0 = *(const f32x4*)p0, x1 = *(const f32x4*)(p0 + 4);
    f32x4 y0 = *(const f32x4*)p1, y1 = *(const f32x4*)(p1 + 4);
    bf16x8 a0, a1;
#pragma unroll
    for (int u = 0; u < 4; ++u) {
      a0[u] = (bf16_t)x0[u]; a0[u + 4] = (bf16_t)x1[u];
      a1[u] = (bf16_t)y0[u]; a1[u + 4] = (bf16_t)y1[u];
      asum += fabsf(x0[u]) + fabsf(x1[u]) + fabsf(y0[u]) + fabsf(y1[u]);
    }
#pragma unroll
    for (int ni = 0; ni < 4; ++ni) {
      bf16x8 bfr = *(const bf16x8*)&Mt[ni * 16 + lr][kof];
      racc[0][ni] = mfma16(a0, bfr, racc[0][ni]);
      racc[1][ni] = mfma16(a1, bfr, racc[1][ni]);
    }
  }
#pragma unroll
  for (int mi = 0; mi < 2; ++mi)
#pragma unroll
    for (int ni = 0; ni < 4; ++ni)
#pragma unroll
      for (int r = 0; r < 4; ++r) {
        int row = r0 + mi * 16 + kg * 4 + r, col = ni * 16 + lr;
        float v = racc[mi][ni][r];
        if (row < 2) v += inj[row * 64 + col];
        recs[row][col] = (bf16_t)v;
      }

  // ---- phase 1: h_new = tanh(W2 @ tanh(W1 @ [h|rec|nid] + b1) + b2) ----
  const float* hp = h + (size_t)bc * 8192;
  const float* np2 = nid + (size_t)c * 8192;
  bf16x8 aA[2][6];
#pragma unroll
  for (int mi = 0; mi < 2; ++mi) {
    int row = r0 + mi * 16 + lr;
#pragma unroll
    for (int ks = 0; ks < 6; ++ks) {
      int kof = ks * 32 + kg * 8;
      if (ks < 2)      aA[mi][ks] = ldcvt8(hp + (size_t)row * 64 + kof);
      else if (ks < 4) aA[mi][ks] = *(const bf16x8*)&recs[row][kof - 64];
      else             aA[mi][ks] = ldcvt8(np2 + (size_t)row * 64 + (kof - 128));
    }
  }
  const bf16_t* w1b = wbf;
  const bf16_t* w2b = wbf + 49152;
  const bf16_t* w3b = wbf + 65536;
  const bf16_t* w4b = wbf + 98304;
  f32x4 acc2[2][4] = {};
  for (int hc = 0; hc < 4; ++hc) {
    f32x4 a1[2][4] = {};
#pragma unroll
    for (int ks = 0; ks < 6; ++ks) {
      int kof = ks * 32 + kg * 8;
#pragma unroll
      for (int ni = 0; ni < 4; ++ni) {
        bf16x8 bfr = *(const bf16x8*)(w1b + (size_t)(hc * 64 + ni * 16 + lr) * 192 + kof);
        a1[0][ni] = mfma16(aA[0][ks], bfr, a1[0][ni]);
        a1[1][ni] = mfma16(aA[1][ks], bfr, a1[1][ni]);
      }
    }
#pragma unroll
    for (int mi = 0; mi < 2; ++mi)
#pragma unroll
      for (int ni = 0; ni < 4; ++ni) {
        float bias = sb1[hc * 64 + ni * 16 + lr];
#pragma unroll
        for (int r = 0; r < 4; ++r)
          hs[r0 + mi * 16 + kg * 4 + r][ni * 16 + lr] = (bf16_t)fast_tanh(a1[mi][ni][r] + bias);
      }
#pragma unroll
    for (int ks = 0; ks < 2; ++ks) {
      int kof = ks * 32 + kg * 8;
      bf16x8 af0 = *(const bf16x8*)&hs[r0 + lr][kof];
      bf16x8 af1 = *(const bf16x8*)&hs[r0 + 16 + lr][kof];
#pragma unroll
      for (int ni = 0; ni < 4; ++ni) {
        bf16x8 bfr = *(const bf16x8*)(w2b + (size_t)(ni * 16 + lr) * 256 + hc * 64 + kof);
        acc2[0][ni] = mfma16(af0, bfr, acc2[0][ni]);
        acc2[1][ni] = mfma16(af1, bfr, acc2[1][ni]);
      }
    }
  }
  float* ohp = out_h + (size_t)bc * 8192;
  float hpart[4] = {0.f, 0.f, 0.f, 0.f};
#pragma unroll
  for (int mi = 0; mi < 2; ++mi)
#pragma unroll
    for (int ni = 0; ni < 4; ++ni) {
      float bias = sb2[ni * 16 + lr];
#pragma unroll
      for (int r = 0; r < 4; ++r) {
        int row = r0 + mi * 16 + kg * 4 + r, col = ni * 16 + lr;
        float v = fast_tanh(acc2[mi][ni][r] + bias);
        ohp[row * 64 + col] = v;
        hnew[row][col] = (bf16_t)v;
        hpart[ni] += v;
      }
    }
#pragma unroll
  for (int ni = 0; ni < 4; ++ni) {  // reduce over kg lanes -> wave col sum
    float s = hpart[ni];
    s += __shfl_xor(s, 16);
    s += __shfl_xor(s, 32);
    if (l < 16) hsum[wave][ni * 16 + l] = s;
  }

  // ---- phase 2: msg_new; k: 0-63 h_new (hnew), 64-127 received (recs) ----
  bf16x8 aB[2][4];
#pragma unroll
  for (int mi = 0; mi < 2; ++mi) {
    int row = r0 + mi * 16 + lr;
#pragma unroll
    for (int ks = 0; ks < 4; ++ks) {
      int kof = ks * 32 + kg * 8;
      if (ks < 2) aB[mi][ks] = *(const bf16x8*)&hnew[row][kof];
      else        aB[mi][ks] = *(const bf16x8*)&recs[row][kof - 64];
    }
  }
  f32x4 acc3[2][4] = {};
  for (int hc = 0; hc < 4; ++hc) {
    f32x4 g3[2][4] = {};
#pragma unroll
    for (int ks = 0; ks < 4; ++ks) {
      int kof = ks * 32 + kg * 8;
#pragma unroll
      for (int ni = 0; ni < 4; ++ni) {
        bf16x8 bfr = *(const bf16x8*)(w3b + (size_t)(hc * 64 + ni * 16 + lr) * 128 + kof);
        g3[0][ni] = mfma16(aB[0][ks], bfr, g3[0][ni]);
        g3[1][ni] = mfma16(aB[1][ks], bfr, g3[1][ni]);
      }
    }
#pragma unroll
    for (int mi = 0; mi < 2; ++mi)
#pragma unroll
      for (int ni = 0; ni < 4; ++ni) {
        float bias = msb1[hc * 64 + ni * 16 + lr];
#pragma unroll
        for (int r = 0; r < 4; ++r)
          hs[r0 + mi * 16 + kg * 4 + r][ni * 16 + lr] = (bf16_t)fast_tanh(g3[mi][ni][r] + bias);
      }
#pragma unroll
    for (int ks = 0; ks < 2; ++ks) {
      int kof = ks * 32 + kg * 8;
      bf16x8 af0 = *(const bf16x8*)&hs[r0 + lr][kof];
      bf16x8 af1 = *(const bf16x8*)&hs[r0 + 16 + lr][kof];
#pragma unroll
      for (int ni = 0; ni < 4; ++ni) {
        bf16x8 bfr = *(const bf16x8*)(w4b + (size_t)(ni * 16 + lr) * 256 + hc * 64 + kof);
        acc3[0][ni] = mfma16(af0, bfr, acc3[0][ni]);
        acc3[1][ni] = mfma16(af1, bfr, acc3[1][ni]);
      }
    }
  }
  float* omp = out_m + (size_t)bc * 8192;
  float mpart[4] = {0.f, 0.f, 0.f, 0.f};
#pragma unroll
  for (int mi = 0; mi < 2; ++mi)
#pragma unroll
    for (int ni = 0; ni < 4; ++ni) {
      float bias = msb2[ni * 16 + lr];
#pragma unroll
      for (int r = 0; r < 4; ++r) {
        int row = r0 + mi * 16 + kg * 4 + r, col = ni * 16 + lr;
        float v = fast_tanh(acc3[mi][ni][r] + bias);
        omp[row * 64 + col] = v;
        mpart[ni] += v;
      }
    }
#pragma unroll
  for (int ni = 0; ni < 4; ++ni) {
    float s = mpart[ni];
    s += __shfl_xor(s, 16);
    s += __shfl_xor(s, 32);
    if (l < 16) msum[wave][ni * 16 + l] = s;
  }
  {  // |W| wave reduce
    float s = asum;
#pragma unroll
    for (int off = 32; off > 0; off >>= 1) s += __shfl_xor(s, off);
    if (l == 0) wsum[wave] = s;
  }
  // decay mean by wave 3
  if (wave == 3) {
    float s = decay[(size_t)bc * 128 + l] + decay[(size_t)bc * 128 + 64 + l];
#pragma unroll
    for (int off = 32; off > 0; off >>= 1) s += __shfl_xor(s, off);
    if (l == 0) modin[129] = s * (1.f / 128.f);
  }
  __syncthreads();  // hsum/msum/wsum/modin[129] ready

  if (t < 64)
    modin[t] = (hsum[0][t] + hsum[1][t] + hsum[2][t] + hsum[3][t]) * (1.f / 128.f);
  else if (t < 128) {
    int d = t - 64;
    modin[64 + d] = (msum[0][d] + msum[1][d] + msum[2][d] + msum[3][d]) * (1.f / 128.f);
  } else if (t == 128)
    modin[128] = (wsum[0] + wsum[1] + wsum[2] + wsum[3]) * (1.f / 16384.f);
  else if (t == 130) modin[130] = rdrift[bc];
  else if (t == 131) modin[131] = sml[b];
  else if (t == 132) modin[132] = smf[b];
  __syncthreads();  // modin ready

  if (t < 64) {  // modulator layer 1 (f32 exact)
    const float* w = mw1 + (size_t)c * 133 * 64;
    float a = mb1[c * 64 + t];
    for (int i = 0; i < 133; ++i) a += modin[i] * w[i * 64 + t];
    hidden[((size_t)(c * 64 + t)) * 8 + b] = fast_tanh(a);
  }
}

// ---- K2: mod_out = hidden @ mod_w2 + b2; W_new = W + dW; decay_new ----
__global__ __launch_bounds__(256) void k_apply(
    const float* __restrict__ hidden, const float* __restrict__ mw2,
    const float* __restrict__ mb2, const float* __restrict__ W,
    const float* __restrict__ decay, float* __restrict__ out_W,
    float* __restrict__ out_d) {
  int c = blockIdx.y, ch = blockIdx.x, t = threadIdx.x;
  int o = ch * 1024 + t * 4;
  if (o >= 16512) return;
  const float* w2 = mw2 + (size_t)c * 64 * 16512 + o;
  const float* hq = hidden + (size_t)c * 512;  // [h][b] for this c
  f32x4 bias = *(const f32x4*)(mb2 + (size_t)c * 16512 + o);
  f32x4 acc[8];
#pragma unroll
  for (int b = 0; b < 8; ++b) acc[b] = bias;
  for (int hh = 0; hh < 64; ++hh) {
    f32x4 wv = __builtin_nontemporal_load((const f32x4*)(w2 + (size_t)hh * 16512));
    f32x4 h0 = *(const f32x4*)(hq + hh * 8);
    f32x4 h1 = *(const f32x4*)(hq + hh * 8 + 4);
#pragma unroll
    for (int b = 0; b < 4; ++b) { acc[b] += h0[b] * wv; acc[b + 4] += h1[b] * wv; }
  }
  if (o < 16384) {
#pragma unroll
    for (int b = 0; b < 8; ++b) {
      size_t idx = (size_t)(b * 64 + c) * 16384 + o;
      f32x4 wv = *(const f32x4*)(W + idx);
      __builtin_nontemporal_store(wv + acc[b], (f32x4*)(out_W + idx));
    }
  } else {
    int i = o - 16384;
#pragma unroll
    for (int b = 0; b < 8; ++b) {
      size_t idx = (size_t)(b * 64 + c) * 128 + i;
      f32x4 dv = *(const f32x4*)(decay + idx);
      __builtin_nontemporal_store(dv + acc[b], (f32x4*)(out_d + idx));
    }
  }
}

extern "C" void kernel_launch(void* const* d_in, const int* in_sizes, int n_in,
                              void* d_out, int out_size, void* d_ws, size_t ws_size,
                              hipStream_t stream) {
  const float* h = (const float*)d_in[0];
  const float* msg = (const float*)d_in[1];
  const float* W = (const float*)d_in[2];
  const float* decay = (const float*)d_in[3];
  const float* rdrift = (const float*)d_in[4];
  const float* sml = (const float*)d_in[5];
  const float* smf = (const float*)d_in[6];
  const float* Haug = (const float*)d_in[7];
  const float* nid = (const float*)d_in[8];
  const float* sw1 = (const float*)d_in[9];
  const float* sb1 = (const float*)d_in[10];
  const float* sw2 = (const float*)d_in[11];
  const float* sb2 = (const float*)d_in[12];
  const float* mw1 = (const float*)d_in[13];
  const float* mb1 = (const float*)d_in[14];
  const float* mw2 = (const float*)d_in[15];
  const float* mb2 = (const float*)d_in[16];
  const float* injw = (const float*)d_in[17];
  const float* injb = (const float*)d_in[18];
  const float* modw1 = (const float*)d_in[19];
  const float* modb1 = (const float*)d_in[20];
  const float* modw2 = (const float*)d_in[21];
  const float* modb2 = (const float*)d_in[22];

  float* out = (float*)d_out;
  float* out_h = out;                // [8,64,128,64]
  float* out_m = out + 4194304;      // [8,64,128,64]
  float* out_W = out + 8388608;      // [8,64,128,128]
  float* out_d = out + 16777216;     // [8,64,128]

  char* wsb = (char*)d_ws;
  bf16_t* wbf = (bf16_t*)wsb;                  // 229 KB (pad to 256 KB)
  float* hidden = (float*)(wsb + 262144);      // 128 KB, [c][h][b]

  k_convert<<<448, 256, 0, stream>>>(sw1, sw2, mw1, mw2, wbf);
  k_fused<<<512, 256, 0, stream>>>(W, msg, h, nid, Haug, injw, injb, wbf,
                                   sb1, sb2, mb1, mb2, decay, rdrift, sml, smf,
                                   modw1, modb1, out_h, out_m, hidden);
  k_apply<<<dim3(17, 64), 256, 0, stream>>>(hidden, modw2, modb2, W, decay, out_W, out_d);
}